// Round 6
// baseline (64.374 us; speedup 1.0000x reference)
//
#include <hip/hip_runtime.h>

#define CC   14      // num labels
#define MAXT 13      // max trials
#define TPB  256
#define RAMP_CAP 1.8f

// harmonic numbers, fp32 chain in reference cumsum order
constexpr float H2  = 1.0f + 0.5f;
constexpr float H3  = H2  + (1.0f/3.0f);
constexpr float H4  = H3  + 0.25f;
constexpr float H5  = H4  + 0.2f;
constexpr float H6  = H5  + (1.0f/6.0f);
constexpr float H7  = H6  + (1.0f/7.0f);
constexpr float H14 = H7 + 0.125f + (1.0f/9.0f) + 0.1f + (1.0f/11.0f)
                         + (1.0f/12.0f) + (1.0f/13.0f) + (1.0f/14.0f);

// One positive label. J, PAR compile-time -> float4 phase SH static.
// Loads trials 0..3 (2 aligned float4); tail trials 4..12 are a ~0.3% path.
template<int PAR, int J>
__device__ __forceinline__ void do_label(unsigned pm, int nn, float fnn,
                                         const float* __restrict__ rowF,
                                         const float (&x)[CC], float& lw)
{
    if ((pm >> J) & 1u) {
        constexpr int SH = (J + 2 * PAR) & 3;        // (182*row+13J) mod 4
        const float* qp = rowF + (13 * J - SH);       // 16B-aligned
        float4 q0 = *(const float4*)(qp);
        float4 q1 = *(const float4*)(qp + 4);
        const float e[8] = {q0.x,q0.y,q0.z,q0.w, q1.x,q1.y,q1.z,q1.w};

        // one pass over row: neg_sum + resolving-negative bitmask (k-order)
        const float m1 = 1.0f - x[J];
        float nsum = 0.f; unsigned gm = 0; int cnt = 0;
        #pragma unroll
        for (int k = 0; k < CC; ++k) {
            if (!((pm >> k) & 1u)) {
                nsum += fminf(fmaxf(x[J] - x[k], 0.f), RAMP_CAP);
                if (m1 + x[k] >= 0.f) gm |= (1u << cnt);   // ref association
                ++cnt;
            }
        }

        unsigned bits = 0;
        #pragma unroll
        for (int t = 0; t < 4; ++t) {                 // trials 0..3, static idx
            int ti = (int)(e[SH + t] * fnn);          // trunc == astype(int32)
            ti = ti < 0 ? 0 : ti;
            ti = ti > nn - 1 ? nn - 1 : ti;
            bits |= ((gm >> ti) & 1u) << t;
        }
        if (bits == 0u) {                             // rare: P ~ 0.24^4
            #pragma unroll
            for (int t = 4; t < MAXT; ++t) {
                int ti = (int)(rowF[13 * J + t] * fnn);
                ti = ti < 0 ? 0 : ti;
                ti = ti > nn - 1 ? nn - 1 : ti;
                bits |= ((gm >> ti) & 1u) << t;
            }
        }
        const int nt = bits ? __ffs(bits) : MAXT;     // num_trials
        const float wt = (nt == 1) ? H14 : (nt == 2) ? H7
                       : (nt == 3) ? H5  : (nt == 4) ? H4
                       : (nt <= 6) ? H3  : H2;        // L[13 // nt]
        lw += wt * nsum;
    }
}

// one row, one label-class c (wave-uniform). PAR = row parity.
template<int PAR>
__device__ __forceinline__ float row_part(int row, int c,
    const float* __restrict__ inp, const int* __restrict__ target,
    const float* __restrict__ S, const float* __restrict__ rand_u)
{
    float x[CC];
    {
        const float* b = inp + (size_t)row * CC;
        if constexpr (PAR == 0) {
            float4 a0 = *(const float4*)(b);
            float4 a1 = *(const float4*)(b + 4);
            float4 a2 = *(const float4*)(b + 8);
            float2 a3 = *(const float2*)(b + 12);
            x[0]=a0.x; x[1]=a0.y; x[2]=a0.z; x[3]=a0.w;
            x[4]=a1.x; x[5]=a1.y; x[6]=a1.z; x[7]=a1.w;
            x[8]=a2.x; x[9]=a2.y; x[10]=a2.z; x[11]=a2.w;
            x[12]=a3.x; x[13]=a3.y;
        } else {
            float2 a0 = *(const float2*)(b);
            float4 a1 = *(const float4*)(b + 2);
            float4 a2 = *(const float4*)(b + 6);
            float4 a3 = *(const float4*)(b + 10);
            x[0]=a0.x; x[1]=a0.y;
            x[2]=a1.x; x[3]=a1.y; x[4]=a1.z; x[5]=a1.w;
            x[6]=a2.x; x[7]=a2.y; x[8]=a2.z; x[9]=a2.w;
            x[10]=a3.x; x[11]=a3.y; x[12]=a3.z; x[13]=a3.w;
        }
    }
    unsigned pm = 0;
    {
        const int* b = target + (size_t)row * CC;
        int tg[CC];
        if constexpr (PAR == 0) {
            int4 a0 = *(const int4*)(b);
            int4 a1 = *(const int4*)(b + 4);
            int4 a2 = *(const int4*)(b + 8);
            int2 a3 = *(const int2*)(b + 12);
            tg[0]=a0.x; tg[1]=a0.y; tg[2]=a0.z; tg[3]=a0.w;
            tg[4]=a1.x; tg[5]=a1.y; tg[6]=a1.z; tg[7]=a1.w;
            tg[8]=a2.x; tg[9]=a2.y; tg[10]=a2.z; tg[11]=a2.w;
            tg[12]=a3.x; tg[13]=a3.y;
        } else {
            int2 a0 = *(const int2*)(b);
            int4 a1 = *(const int4*)(b + 2);
            int4 a2 = *(const int4*)(b + 6);
            int4 a3 = *(const int4*)(b + 10);
            tg[0]=a0.x; tg[1]=a0.y;
            tg[2]=a1.x; tg[3]=a1.y; tg[4]=a1.z; tg[5]=a1.w;
            tg[6]=a2.x; tg[7]=a2.y; tg[8]=a2.z; tg[9]=a2.w;
            tg[10]=a3.x; tg[11]=a3.y; tg[12]=a3.z; tg[13]=a3.w;
        }
        #pragma unroll
        for (int k = 0; k < CC; ++k) if (tg[k] != 0) pm |= (1u << k);
    }
    const int nn = CC - __popc(pm);

    float lw = 0.f;
    if (pm != 0u && nn > 0) {
        const float fnn = (float)nn;
        const float* rowF = rand_u + (size_t)row * (CC * MAXT);
        switch (c) {    // wave-uniform -> scalar branch, 3 cases skipped
        case 0:
            do_label<PAR, 0>(pm, nn, fnn, rowF, x, lw);
            do_label<PAR, 4>(pm, nn, fnn, rowF, x, lw);
            do_label<PAR, 8>(pm, nn, fnn, rowF, x, lw);
            do_label<PAR,12>(pm, nn, fnn, rowF, x, lw);
            break;
        case 1:
            do_label<PAR, 1>(pm, nn, fnn, rowF, x, lw);
            do_label<PAR, 5>(pm, nn, fnn, rowF, x, lw);
            do_label<PAR, 9>(pm, nn, fnn, rowF, x, lw);
            do_label<PAR,13>(pm, nn, fnn, rowF, x, lw);
            break;
        case 2:
            do_label<PAR, 2>(pm, nn, fnn, rowF, x, lw);
            do_label<PAR, 6>(pm, nn, fnn, rowF, x, lw);
            do_label<PAR,10>(pm, nn, fnn, rowF, x, lw);
            break;
        default:
            do_label<PAR, 3>(pm, nn, fnn, rowF, x, lw);
            do_label<PAR, 7>(pm, nn, fnn, rowF, x, lw);
            do_label<PAR,11>(pm, nn, fnn, rowF, x, lw);
            break;
        }
    }

    float v = lw;
    if (c == 0) {                       // kappa counted once per row
        float kap = 0.f;
        #pragma unroll
        for (int k = 0; k < CC; ++k) {
            if ((pm >> k) & 1u) kap += fminf(fmaxf(1.0f - x[k], 0.f), RAMP_CAP);
            else                kap += 1.0f;
        }
        v += 2.0f * kap;
    }
    const float si = (row <= 14) ? 1.0f : S[row - 14];
    return si * v;
}

__global__ __launch_bounds__(TPB) void rwl_kernel(
    const float* __restrict__ inp, const int* __restrict__ target,
    const float* __restrict__ S, const float* __restrict__ rand_u,
    float* __restrict__ out, int B)
{
    __shared__ float s_red[4];
    const int tid  = threadIdx.x;
    // block owns 64 row-pairs; its 4 waves cover label-classes 0..3
    const int p = blockIdx.x * 64 + (tid & 63);        // row-pair index
    const int c = __builtin_amdgcn_readfirstlane(tid >> 6);  // provably uniform
    const int r0 = p * 2, r1 = r0 + 1;

    float total = 0.f;
    if (r0 < B) total += row_part<0>(r0, c, inp, target, S, rand_u);
    if (r1 < B) total += row_part<1>(r1, c, inp, target, S, rand_u);

    #pragma unroll
    for (int off = 32; off > 0; off >>= 1)
        total += __shfl_down(total, off, 64);
    if ((tid & 63) == 0) s_red[tid >> 6] = total;
    __syncthreads();
    if (tid == 0)
        atomicAdd(out, s_red[0] + s_red[1] + s_red[2] + s_red[3]);
}

extern "C" void kernel_launch(void* const* d_in, const int* in_sizes, int n_in,
                              void* d_out, int out_size, void* d_ws, size_t ws_size,
                              hipStream_t stream) {
    const float* inp    = (const float*)d_in[0];
    const int*   target = (const int*)d_in[1];
    const float* S      = (const float*)d_in[2];
    const float* ru     = (const float*)d_in[3];
    float*       out    = (float*)d_out;
    const int B = in_sizes[2];   // S has B elements

    // d_out is poisoned and not re-zeroed between replays: zero it each call
    hipMemsetAsync(out, 0, sizeof(float), stream);

    const int pairs  = (B + 1) / 2;
    const int blocks = (pairs + 63) / 64;   // 64 pairs per block
    rwl_kernel<<<blocks, TPB, 0, stream>>>(inp, target, S, ru, out, B);
}